// Round 1
// 288.454 us; speedup vs baseline: 1.0315x; 1.0315x over previous
//
#include <hip/hip_runtime.h>
#include <hip/hip_bf16.h>

#define NIN    512
#define NEVAL  1536
#define NCOLS  2048
#define NOUT   256
#define OUT_BASE 1280
#define BK     128
#define NBLK   12       // NEVAL / BK
#define WTS    132      // Wt row stride (floats): 16B-aligned rows, breaks 128-stride banking

typedef __attribute__((ext_vector_type(8))) short short8;   // 8 bf16 (4 VGPRs)
typedef __attribute__((ext_vector_type(4))) float floatx4;  // MFMA C/D

// ---------- helpers ----------

__device__ __forceinline__ unsigned short f2bf(float f) {
    __hip_bfloat16 h = __float2bfloat16(f);
    return __builtin_bit_cast(unsigned short, h);
}
__device__ __forceinline__ unsigned pack2(float a, float b) {
    return (unsigned)f2bf(a) | ((unsigned)f2bf(b) << 16);
}
// sigmoid(clip(5z,-60,60)): clamp dropped — v_exp overflow gives exact 0/1.
__device__ __forceinline__ float sigmoid5(float z) {
    return __builtin_amdgcn_rcpf(1.0f + __expf(-5.0f * z));
}
__device__ __forceinline__ float rdlane(float v, int l) {
    return __builtin_bit_cast(float,
        __builtin_amdgcn_readlane(__builtin_bit_cast(int, v), l));
}

// ---------- W fp32 -> bf16 (d_ws re-poisoned every launch, so rerun) ----------

__global__ __launch_bounds__(256) void wconv(const float* __restrict__ W,
                                             ushort* __restrict__ Wb, int n8) {
    int i = blockIdx.x * blockDim.x + threadIdx.x;
    if (i < n8) {
        float4 v0 = ((const float4*)W)[2 * i];
        float4 v1 = ((const float4*)W)[2 * i + 1];
        uint4 pk;
        pk.x = pack2(v0.x, v0.y); pk.y = pack2(v0.z, v0.w);
        pk.z = pack2(v1.x, v1.y); pk.w = pack2(v1.z, v1.w);
        ((uint4*)Wb)[i] = pk;
    }
}

// ---------- main kernel ----------
// 256 WGs x 1024 threads (16 waves), 1 WG/CU. WG owns 16 batch rows; wave w =
// row w for the chain. O[16][2048] bf16 in LDS, row r rotated by 8r elements.
// ROUND-13: BK=128 (NBLK 24->12). R8-R12 established time = NBLK*F + V with
// per-block FIXED cost F dominant (VALU 46%, MFMA 2.6%, HBM ~1%). Halving the
// block count halves barrier pairs / load drains / gathers; total chain steps
// (1536) and total MFMA work unchanged.
// Phase-A roles: 8 node-groups (w>>1) x 2 K-split slots (w&1, stride 64).
// Chunk (32-col) ownership is STATIC: parity(chunk) == ksp, consistent across
// prologue/main/tail.
// Chain: lane ii holds nodes i0+ii (zacc0) and i0+64+ii (zacc1). Steps 0..63
// broadcast from zacc0 and update both (W[ii][jj] upper part is 0 in memory);
// steps 64..127 broadcast from zacc1 and update zacc1 only.
// Wt is NON-transposed [node][col] stride 132: staging = 4 coalesced b128
// writes/thread; chain reads its own weight row as one b128 per 4 steps
// (conflict-free, pipelined one group ahead).

__global__ __launch_bounds__(1024) void ffnet(const float* __restrict__ x,
                                              const float* __restrict__ W,
                                              const ushort* __restrict__ Wb,
                                              const float* __restrict__ bias,
                                              float* __restrict__ out) {
    __shared__ unsigned short O[16 * 2048];   // 64 KB
    __shared__ float Zred[16 * 256];          // 16 KB  [wave][lane][reg]
    __shared__ float Wt[BK * WTS];            // 67.6 KB diag block [node][col]

    const int t    = threadIdx.x;
    const int w    = t >> 6;        // wave 0..15
    const int lane = t & 63;

    // phase-A role
    const int m16  = lane & 15;     // A row (batch row) / D col (node in group)
    const int quad = lane >> 4;     // 0..3
    const int ng   = w >> 1;        // node group 0..7 (16 nodes each)
    const int ksp  = w & 1;         // K-split slot, stride 64
    const int arow = m16 << 11;
    const int arot = m16 << 3;

    // chain role: wave w owns local row w; lane ii = node pair (ii, ii+64)
    const int ii   = lane;
    const long row = (long)blockIdx.x * 16 + w;
    const int rot  = w << 3;

    // Wt staging role: node sn (0..127), col base sc (0,16,..,112)
    const int sn = t >> 3;
    const int sc = (t & 7) << 4;

    // ---- stage x row w into LDS as bf16 (swizzled) ----
    {
        const float* xr = x + row * NIN + lane * 8;
        float4 v0 = *(const float4*)xr;
        float4 v1 = *(const float4*)(xr + 4);
        uint4 pk;
        pk.x = pack2(v0.x, v0.y); pk.y = pack2(v0.z, v0.w);
        pk.z = pack2(v1.x, v1.y); pk.w = pack2(v1.z, v1.w);
        *(uint4*)&O[(w << 11) + ((lane * 8 + rot) & 2047)] = pk;
    }
    __syncthreads();

    // ---- prologue: main(0) over columns [0, 384) (chunks 0..11) ----
    floatx4 acc = {0.f, 0.f, 0.f, 0.f};
    {
        const ushort* wb = Wb + (size_t)(ng * 16 + m16) * NCOLS;
        #pragma unroll
        for (int c = 0; c < (NIN - BK) / 64; ++c) {
            const int kk = ksp * 32 + c * 64;
            short8 a = *(const short8*)&O[arow + ((kk + quad * 8 + arot) & 2047)];
            short8 b = *(const short8*)&wb[kk + quad * 8];
            acc = __builtin_amdgcn_mfma_f32_16x16x32_bf16(a, b, acc, 0, 0, 0);
        }
    }

    for (int k = 0; k < NBLK; ++k) {
        const int i0 = k << 7;
        const int L0 = NIN + i0;

        __syncthreads();            // barrier A: chain(k-1) O/Wt-reads done

        // issue Wt 128x128 diag load (16 floats/thread) + biases early
        const float* wsrc = &W[(size_t)(i0 + sn) * NCOLS + L0 + sc];
        float4 wv0 = ((const float4*)wsrc)[0];
        float4 wv1 = ((const float4*)wsrc)[1];
        float4 wv2 = ((const float4*)wsrc)[2];
        float4 wv3 = ((const float4*)wsrc)[3];
        float bi0 = bias[i0 + ii];
        float bi1 = bias[i0 + 64 + ii];

        // issue main(k+1) over [0, L0) — drains overlap Wt stage + barrier B
        floatx4 accN = {0.f, 0.f, 0.f, 0.f};
        if (k + 1 < NBLK) {
            const ushort* wb = Wb + (size_t)(i0 + BK + ng * 16 + m16) * NCOLS;
            #pragma unroll 4
            for (int kk = ksp * 32; kk < L0; kk += 64) {
                short8 a = *(const short8*)&O[arow + ((kk + quad * 8 + arot) & 2047)];
                short8 b = *(const short8*)&wb[kk + quad * 8];
                accN = __builtin_amdgcn_mfma_f32_16x16x32_bf16(a, b, accN, 0, 0, 0);
            }
        }

        // stage diag weights row-major (coalesced b128 writes)
        {
            float4* wd = (float4*)&Wt[sn * WTS + sc];
            wd[0] = wv0; wd[1] = wv1; wd[2] = wv2; wd[3] = wv3;
        }

        // tail: 2 K=32 MFMAs over [L0-128, L0): chunk parity == ksp
        {
            const ushort* wb = Wb + (size_t)(i0 + ng * 16 + m16) * NCOLS;
            const int ts0 = L0 - 128 + ksp * 32;
            short8 a0 = *(const short8*)&O[arow + ((ts0 + quad * 8 + arot) & 2047)];
            short8 b0 = *(const short8*)&wb[ts0 + quad * 8];
            acc = __builtin_amdgcn_mfma_f32_16x16x32_bf16(a0, b0, acc, 0, 0, 0);
            const int ts1 = ts0 + 64;
            short8 a1 = *(const short8*)&O[arow + ((ts1 + quad * 8 + arot) & 2047)];
            short8 b1 = *(const short8*)&wb[ts1 + quad * 8];
            acc = __builtin_amdgcn_mfma_f32_16x16x32_bf16(a1, b1, acc, 0, 0, 0);
        }

        // D frag: lane q*16+n holds Z[m=4q+reg][n]
        *(floatx4*)&Zred[(w << 8) + (lane << 2)] = acc;
        __syncthreads();            // barrier B: Zred + Wt visible

        // gather z for (row w, nodes i0+ii / i0+64+ii): 2 K-split partials each
        const int base = ((w >> 2) << 6) + ((ii & 15) << 2) + (w & 3);
        const int g0w  = (ii >> 4) << 1;     // wave pair for zacc0's node group
        float zacc0 = bi0 + Zred[(g0w << 8) + base] + Zred[((g0w + 1) << 8) + base];
        float zacc1 = bi1 + Zred[((g0w + 8) << 8) + base] + Zred[((g0w + 9) << 8) + base];

        // chain: 128 sequential sigmoid steps, all 64 lanes.
        // Weight row reads: one b128 per 4 steps, pipelined one group ahead.
        const float* wr0 = &Wt[ii * WTS];
        const float* wr1 = &Wt[(ii + 64) * WTS];
        float4 w0 = *(const float4*)wr0;
        float4 w1 = *(const float4*)wr1;
        #pragma unroll
        for (int j0 = 0; j0 < 64; j0 += 4) {
            float4 nw0 = w0, nw1 = w1;
            if (j0 < 60) {
                nw0 = *(const float4*)(wr0 + j0 + 4);
                nw1 = *(const float4*)(wr1 + j0 + 4);
            } else {
                nw1 = *(const float4*)(wr1 + 64);   // first group of 2nd half
            }
            { float o = sigmoid5(rdlane(zacc0, j0 + 0));
              zacc0 = fmaf(w0.x, o, zacc0); zacc1 = fmaf(w1.x, o, zacc1); }
            { float o = sigmoid5(rdlane(zacc0, j0 + 1));
              zacc0 = fmaf(w0.y, o, zacc0); zacc1 = fmaf(w1.y, o, zacc1); }
            { float o = sigmoid5(rdlane(zacc0, j0 + 2));
              zacc0 = fmaf(w0.z, o, zacc0); zacc1 = fmaf(w1.z, o, zacc1); }
            { float o = sigmoid5(rdlane(zacc0, j0 + 3));
              zacc0 = fmaf(w0.w, o, zacc0); zacc1 = fmaf(w1.w, o, zacc1); }
            w0 = nw0; w1 = nw1;
        }
        #pragma unroll
        for (int j0 = 64; j0 < 128; j0 += 4) {
            float4 nw1 = w1;
            if (j0 < 124) nw1 = *(const float4*)(wr1 + j0 + 4);
            { float o = sigmoid5(rdlane(zacc1, j0 - 64));
              zacc1 = fmaf(w1.x, o, zacc1); }
            { float o = sigmoid5(rdlane(zacc1, j0 - 63));
              zacc1 = fmaf(w1.y, o, zacc1); }
            { float o = sigmoid5(rdlane(zacc1, j0 - 62));
              zacc1 = fmaf(w1.z, o, zacc1); }
            { float o = sigmoid5(rdlane(zacc1, j0 - 61));
              zacc1 = fmaf(w1.w, o, zacc1); }
            w1 = nw1;
        }

        float o0 = sigmoid5(zacc0);
        float o1 = sigmoid5(zacc1);
        O[(w << 11) + ((L0 + ii + rot) & 2047)]      = f2bf(o0);
        O[(w << 11) + ((L0 + 64 + ii + rot) & 2047)] = f2bf(o1);
        const int g0 = i0 + ii;                 // OUT_BASE is 128-aligned, so
        if (g0 >= OUT_BASE) {                   // g0/g1 qualify together
            out[row * NOUT + (g0 - OUT_BASE)]      = o0;
            out[row * NOUT + (g0 + 64 - OUT_BASE)] = o1;
        }

        acc = accN;
    }
}

// ---------- launch ----------

extern "C" void kernel_launch(void* const* d_in, const int* in_sizes, int n_in,
                              void* d_out, int out_size, void* d_ws, size_t ws_size,
                              hipStream_t stream) {
    const float* x  = (const float*)d_in[0];   // [4096, 512]
    const float* W  = (const float*)d_in[1];   // [1536, 2048]
    const float* b  = (const float*)d_in[2];   // [1536]
    float* out = (float*)d_out;                // [4096, 256]
    ushort* Wb = (ushort*)d_ws;                // bf16 W copy (6.3 MB)

    int n8 = NEVAL * NCOLS / 8;
    wconv<<<n8 / 256, 256, 0, stream>>>(W, Wb, n8);
    ffnet<<<4096 / 16, 1024, 0, stream>>>(x, W, Wb, b, out);
}

// Round 2
// 276.777 us; speedup vs baseline: 1.0750x; 1.0422x over previous
//
#include <hip/hip_runtime.h>
#include <hip/hip_bf16.h>

#define NIN    512
#define NEVAL  1536
#define NCOLS  2048
#define NOUT   256
#define OUT_BASE 1280
#define BK     64
#define NBLK   24       // NEVAL / BK
#define WTS    68       // Wt row stride (floats): 16B-aligned, stride-68 b128 reads conflict-free

typedef __attribute__((ext_vector_type(8))) short short8;   // 8 bf16 (4 VGPRs)
typedef __attribute__((ext_vector_type(4))) float floatx4;  // MFMA C/D

#define C5 (-7.21347520444481703f)   // -5 * log2(e): sigmoid(5z) = rcp(1+exp2(C5*z))

// ---------- helpers ----------

__device__ __forceinline__ unsigned short f2bf(float f) {
    __hip_bfloat16 h = __float2bfloat16(f);
    return __builtin_bit_cast(unsigned short, h);
}
__device__ __forceinline__ unsigned pack2(float a, float b) {
    return (unsigned)f2bf(a) | ((unsigned)f2bf(b) << 16);
}
// sigmoid in folded domain: y = C5*z; sigma = rcp(1+exp2(y)). exp2 overflow -> +inf -> rcp=0 (exact).
__device__ __forceinline__ float sig2(float y) {
    return __builtin_amdgcn_rcpf(1.0f + __builtin_amdgcn_exp2f(y));
}
__device__ __forceinline__ float rdlane(float v, int l) {
    return __builtin_bit_cast(float,
        __builtin_amdgcn_readlane(__builtin_bit_cast(int, v), l));
}

// ---------- W fp32 -> bf16 (d_ws re-poisoned every launch, so rerun) ----------

__global__ __launch_bounds__(256) void wconv(const float* __restrict__ W,
                                             ushort* __restrict__ Wb, int n8) {
    int i = blockIdx.x * blockDim.x + threadIdx.x;
    if (i < n8) {
        float4 v0 = ((const float4*)W)[2 * i];
        float4 v1 = ((const float4*)W)[2 * i + 1];
        uint4 pk;
        pk.x = pack2(v0.x, v0.y); pk.y = pack2(v0.z, v0.w);
        pk.z = pack2(v1.x, v1.y); pk.w = pack2(v1.z, v1.w);
        ((uint4*)Wb)[i] = pk;
    }
}

// ---------- main kernel ----------
// ROUND-14: producer/consumer wave specialization. R13 proved time is
// volume-bound (NBLK 24->12 changed nothing): the barrier lockstep makes
// {load/MFMA phase} and {chain phase} ADD. Now they overlap in every slot:
//   C-waves 0..7: chain block k (2 rows each: rA=w, rB=w+8), dual interleaved
//                 dependency chains; on-the-fly tail accumulation for block
//                 k+1 (tn += Wsub[ii][j]*o_j, fp32) kills the tail MFMA.
//   P-waves 8..15: stage Panel(k+1) = C5*W[rows 64(k+1)..+128)][cols of blk
//                 k+1] (diag(k+1)+sub(k+2), dbuf), MFMA main(k+1) over
//                 [0, 512+64k) (4 node-groups x 2 K-slots), write Zp dbuf.
// ONE barrier per slot. Disjointness: P reads O cols [0,512+64k); C writes
// [512+64k,+64). All weights consumed by the chain pre-scaled by C5 so the
// per-step v_mul disappears (exp2 directly on accumulated y).

__global__ __launch_bounds__(1024) void ffnet(const float* __restrict__ x,
                                              const float* __restrict__ W,
                                              const ushort* __restrict__ Wb,
                                              const float* __restrict__ bias,
                                              float* __restrict__ out) {
    __shared__ unsigned short O[16 * 2048];   // 64 KB
    __shared__ float Wt[2][128 * WTS];        // 68 KB: [buf][row 0-63 diag | 64-127 sub][col]
    __shared__ float Zp[2][8 * 256];          // 16 KB: [buf][pwave][frag]

    const int t    = threadIdx.x;
    const int w    = t >> 6;        // wave 0..15
    const int lane = t & 63;
    const bool isC = (w < 8);

    // producer MFMA role
    const int m16  = lane & 15;     // A row (batch row) / D col (node in group)
    const int quad = lane >> 4;
    const int pw   = w & 7;         // producer wave 0..7
    const int ng   = pw >> 1;       // node group 0..3 (16 nodes)
    const int ksp  = pw & 1;        // K-split slot (32-col chunks, stride 64)
    const int arow = m16 << 11;
    const int arot = m16 << 3;

    // producer staging role: panel row sn (0..127), col base sc (0,16,32,48)
    const int pt = t & 511;
    const int sn = pt >> 2;
    const int sc = (pt & 3) << 4;

    // consumer role: rows rA=w, rB=w+8; lane ii = node within block
    const int ii   = lane;
    const int rA   = w, rB = w + 8;
    const long rowA = (long)blockIdx.x * 16 + rA;
    const long rowB = (long)blockIdx.x * 16 + rB;
    const int rotA = rA << 3, rotB = rB << 3;
    const int ia = ((rA >> 2) << 6) + ((ii & 15) << 2) + (rA & 3);
    const int ib = ((rB >> 2) << 6) + ((ii & 15) << 2) + (rB & 3);

    // ---- stage x row w into LDS as bf16 (swizzled); all 16 waves ----
    {
        const long rowS = (long)blockIdx.x * 16 + w;
        const float* xr = x + rowS * NIN + lane * 8;
        float4 v0 = *(const float4*)xr;
        float4 v1 = *(const float4*)(xr + 4);
        uint4 pk;
        pk.x = pack2(v0.x, v0.y); pk.y = pack2(v0.z, v0.w);
        pk.z = pack2(v1.x, v1.y); pk.w = pack2(v1.z, v1.w);
        *(uint4*)&O[(w << 11) + ((lane * 8 + (w << 3)) & 2047)] = pk;
    }
    __syncthreads();

    float tnA = 0.f, tnB = 0.f;     // consumer on-the-fly tail accumulators
    float bnext = 0.f;

    if (!isC) {
        // ---- prologue: stage Panel(0) + main(0) over full [0,512) -> Zp[0]
        {
            const int e = sn;                       // rows [0,128)
            const float* src = W + (size_t)e * NCOLS + NIN + sc;
            float4 v0 = ((const float4*)src)[0];
            float4 v1 = ((const float4*)src)[1];
            float4 v2 = ((const float4*)src)[2];
            float4 v3 = ((const float4*)src)[3];
            v0.x *= C5; v0.y *= C5; v0.z *= C5; v0.w *= C5;
            v1.x *= C5; v1.y *= C5; v1.z *= C5; v1.w *= C5;
            v2.x *= C5; v2.y *= C5; v2.z *= C5; v2.w *= C5;
            v3.x *= C5; v3.y *= C5; v3.z *= C5; v3.w *= C5;
            float4* dst = (float4*)&Wt[0][sn * WTS + sc];
            dst[0] = v0; dst[1] = v1; dst[2] = v2; dst[3] = v3;
        }
        floatx4 acc = {0.f, 0.f, 0.f, 0.f};
        const ushort* wbp = Wb + (size_t)((ng << 4) + m16) * NCOLS;
        #pragma unroll
        for (int kk = ksp * 32; kk < NIN; kk += 64) {
            short8 a = *(const short8*)&O[arow + ((kk + (quad << 3) + arot) & 2047)];
            short8 b = *(const short8*)&wbp[kk + (quad << 3)];
            acc = __builtin_amdgcn_mfma_f32_16x16x32_bf16(a, b, acc, 0, 0, 0);
        }
        *(floatx4*)&Zp[0][(pw << 8) + (lane << 2)] = acc;
    } else {
        bnext = bias[ii];           // bias for block 0
    }
    __syncthreads();                // barrier(0): Zp[0], Wt[0] visible

    for (int k = 0; k < NBLK; ++k) {
        if (isC) {
            // ================= consumer: chain block k =================
            const int i0 = k << 6;
            float bcur = bnext;
            if (k + 1 < NBLK) bnext = bias[((k + 1) << 6) + ii];

            const float* zp = &Zp[k & 1][0];
            const int pw0 = (ii >> 4) << 1;
            float zA = zp[(pw0 << 8) + ia] + zp[(pw0 << 8) + 256 + ia];
            float zB = zp[(pw0 << 8) + ib] + zp[(pw0 << 8) + 256 + ib];
            float sb = C5 * bcur;
            float yA = fmaf(C5, zA, tnA + sb);
            float yB = fmaf(C5, zB, tnB + sb);
            tnA = 0.f; tnB = 0.f;

            const float* wrD = &Wt[k & 1][ii * WTS];
            const float* wrS = &Wt[k & 1][(64 + ii) * WTS];
            float4 d0 = *(const float4*)(wrD);
            float4 s0 = *(const float4*)(wrS);
            float4 d1 = *(const float4*)(wrD + 4);
            float4 s1 = *(const float4*)(wrS + 4);

            #define STEP(wdv, wsv, J) do { \
                float oA_ = sig2(rdlane(yA, (J))); \
                yA = fmaf((wdv), oA_, yA); tnA = fmaf((wsv), oA_, tnA); \
                float oB_ = sig2(rdlane(yB, (J))); \
                yB = fmaf((wdv), oB_, yB); tnB = fmaf((wsv), oB_, tnB); \
            } while (0)

            #pragma unroll
            for (int j0 = 0; j0 < 64; j0 += 8) {
                float4 pd0 = d0, ps0 = s0, pd1 = d1, ps1 = s1;
                if (j0 < 56) {                      // prefetch 2 groups ahead
                    pd0 = *(const float4*)(wrD + j0 + 8);
                    ps0 = *(const float4*)(wrS + j0 + 8);
                    pd1 = *(const float4*)(wrD + j0 + 12);
                    ps1 = *(const float4*)(wrS + j0 + 12);
                }
                STEP(d0.x, s0.x, j0 + 0); STEP(d0.y, s0.y, j0 + 1);
                STEP(d0.z, s0.z, j0 + 2); STEP(d0.w, s0.w, j0 + 3);
                STEP(d1.x, s1.x, j0 + 4); STEP(d1.y, s1.y, j0 + 5);
                STEP(d1.z, s1.z, j0 + 6); STEP(d1.w, s1.w, j0 + 7);
                d0 = pd0; s0 = ps0; d1 = pd1; s1 = ps1;
            }
            #undef STEP

            float oA = sig2(yA);    // lane ii's y is final after step ii (upper-tri zeros)
            float oB = sig2(yB);
            O[(rA << 11) + ((NIN + i0 + ii + rotA) & 2047)] = f2bf(oA);
            O[(rB << 11) + ((NIN + i0 + ii + rotB) & 2047)] = f2bf(oB);
            const int g = i0 + ii;
            if (g >= OUT_BASE) {
                out[rowA * NOUT + (g - OUT_BASE)] = oA;
                out[rowB * NOUT + (g - OUT_BASE)] = oB;
            }
        } else if (k + 1 < NBLK) {
            // ================= producer: block b = k+1 =================
            const int b = k + 1;
            // stage Panel(b): rows e in [64b, 64b+128) clipped, cols [512+64b, +64)
            {
                const int e = (b << 6) + sn;
                if (e < NEVAL) {
                    const float* src = W + (size_t)e * NCOLS + (NIN + (b << 6)) + sc;
                    float4 v0 = ((const float4*)src)[0];
                    float4 v1 = ((const float4*)src)[1];
                    float4 v2 = ((const float4*)src)[2];
                    float4 v3 = ((const float4*)src)[3];
                    v0.x *= C5; v0.y *= C5; v0.z *= C5; v0.w *= C5;
                    v1.x *= C5; v1.y *= C5; v1.z *= C5; v1.w *= C5;
                    v2.x *= C5; v2.y *= C5; v2.z *= C5; v2.w *= C5;
                    v3.x *= C5; v3.y *= C5; v3.z *= C5; v3.w *= C5;
                    float4* dst = (float4*)&Wt[b & 1][sn * WTS + sc];
                    dst[0] = v0; dst[1] = v1; dst[2] = v2; dst[3] = v3;
                }
            }
            // main(b): cols [0, 448+64b) = [0, 512+64k)
            floatx4 acc = {0.f, 0.f, 0.f, 0.f};
            const ushort* wbp = Wb + (size_t)((b << 6) + (ng << 4) + m16) * NCOLS;
            const int hi = (NIN - BK) + (b << 6);
            #pragma unroll 4
            for (int kk = ksp * 32; kk < hi; kk += 64) {
                short8 a = *(const short8*)&O[arow + ((kk + (quad << 3) + arot) & 2047)];
                short8 bb = *(const short8*)&wbp[kk + (quad << 3)];
                acc = __builtin_amdgcn_mfma_f32_16x16x32_bf16(a, bb, acc, 0, 0, 0);
            }
            *(floatx4*)&Zp[b & 1][(pw << 8) + (lane << 2)] = acc;
        }
        __syncthreads();            // end of slot k: Zp/Wt(k+1) + O(N_k) visible
    }
}

// ---------- launch ----------

extern "C" void kernel_launch(void* const* d_in, const int* in_sizes, int n_in,
                              void* d_out, int out_size, void* d_ws, size_t ws_size,
                              hipStream_t stream) {
    const float* x  = (const float*)d_in[0];   // [4096, 512]
    const float* W  = (const float*)d_in[1];   // [1536, 2048]
    const float* b  = (const float*)d_in[2];   // [1536]
    float* out = (float*)d_out;                // [4096, 256]
    ushort* Wb = (ushort*)d_ws;                // bf16 W copy (6.3 MB)

    int n8 = NEVAL * NCOLS / 8;
    wconv<<<n8 / 256, 256, 0, stream>>>(W, Wb, n8);
    ffnet<<<4096 / 16, 1024, 0, stream>>>(x, W, Wb, b, out);
}

// Round 3
// 205.018 us; speedup vs baseline: 1.4512x; 1.3500x over previous
//
#include <hip/hip_runtime.h>
#include <hip/hip_bf16.h>

#define NIN    512
#define NEVAL  1536
#define NCOLS  2048
#define NOUT   256
#define OUT_BASE 1280
#define BK     64
#define NBLK   24       // NEVAL / BK
#define WTS    68       // Wt row stride (floats): b128 reads tile all 32 banks (optimal 8-way)

typedef __attribute__((ext_vector_type(8))) short short8;   // 8 bf16 (4 VGPRs)
typedef __attribute__((ext_vector_type(4))) float floatx4;  // MFMA C/D

#define C5 (-7.21347520444481703f)   // -5 * log2(e): sigmoid(5z) = rcp(1+exp2(C5*z))

// ---------- helpers ----------

__device__ __forceinline__ unsigned short f2bf(float f) {
    __hip_bfloat16 h = __float2bfloat16(f);
    return __builtin_bit_cast(unsigned short, h);
}
__device__ __forceinline__ unsigned pack2(float a, float b) {
    return (unsigned)f2bf(a) | ((unsigned)f2bf(b) << 16);
}
// sigmoid in folded domain: y = C5*z; sigma = rcp(1+exp2(y)). exp2 overflow -> +inf -> rcp=0 (exact).
__device__ __forceinline__ float sig2(float y) {
    return __builtin_amdgcn_rcpf(1.0f + __builtin_amdgcn_exp2f(y));
}
__device__ __forceinline__ float rdlane(float v, int l) {
    return __builtin_bit_cast(float,
        __builtin_amdgcn_readlane(__builtin_bit_cast(int, v), l));
}

// ---------- W fp32 -> bf16 (d_ws re-poisoned every launch, so rerun) ----------

__global__ __launch_bounds__(256) void wconv(const float* __restrict__ W,
                                             ushort* __restrict__ Wb, int n8) {
    int i = blockIdx.x * blockDim.x + threadIdx.x;
    if (i < n8) {
        float4 v0 = ((const float4*)W)[2 * i];
        float4 v1 = ((const float4*)W)[2 * i + 1];
        uint4 pk;
        pk.x = pack2(v0.x, v0.y); pk.y = pack2(v0.z, v0.w);
        pk.z = pack2(v1.x, v1.y); pk.w = pack2(v1.z, v1.w);
        ((uint4*)Wb)[i] = pk;
    }
}

// ---------- main kernel ----------
// ROUND-15: 4 consumer waves x 4 rows (was 8x2). R14's overlap worked but
// VALUBusy stayed 44% -> chain is LATENCY-bound: 2 chains/wave can't hide the
// ~45cyc serial path (fma->readlane->exp2->add->rcp). 4 independent chains
// per wave raise per-step issue to ~96 cyc > latency -> self-hiding. Chain
// weights are shared across the 4 rows (same node block). Freed waves join
// producers: 12 P-waves = 4 node-groups x 3 K-slots (chunk c owner: c%3).
//   C-waves 0..3:  rows 4w..4w+3; chain block k; on-the-fly tail (tn) for k+1.
//   P-waves 4..15: stage Panel(k+1) (waves 4..11), MFMA main(k+1) over
//                  [0, 448+64(k+1)), write Zp[(k+1)&1].
// ONE barrier per slot. Disjoint: P reads O cols [0,512+64k); C writes
// [512+64k,+64). Chain weights pre-scaled by C5 (exp2 direct).

__global__ __launch_bounds__(1024) void ffnet(const float* __restrict__ x,
                                              const float* __restrict__ W,
                                              const ushort* __restrict__ Wb,
                                              const float* __restrict__ bias,
                                              float* __restrict__ out) {
    __shared__ unsigned short O[16 * 2048];   // 64 KB
    __shared__ float Wt[2][128 * WTS];        // 69.6 KB: [buf][row 0-63 diag | 64-127 sub][col]
    __shared__ float Zp[2][12 * 256];         // 24 KB: [buf][pwave][frag]

    const int t    = threadIdx.x;
    const int w    = t >> 6;        // wave 0..15
    const int lane = t & 63;
    const bool isC = (w < 4);

    // producer MFMA frag role
    const int m16  = lane & 15;     // A row (batch row) / D col (node in group)
    const int quad = lane >> 4;
    const int arow = m16 << 11;
    const int arot = m16 << 3;

    // consumer role: rows 4w..4w+3; lane ii = node within block
    const int ii   = lane;

    // ---- stage x row w into LDS as bf16 (swizzled); all 16 waves ----
    {
        const long rowS = (long)blockIdx.x * 16 + w;
        const float* xr = x + rowS * NIN + lane * 8;
        float4 v0 = *(const float4*)xr;
        float4 v1 = *(const float4*)(xr + 4);
        uint4 pk;
        pk.x = pack2(v0.x, v0.y); pk.y = pack2(v0.z, v0.w);
        pk.z = pack2(v1.x, v1.y); pk.w = pack2(v1.z, v1.w);
        *(uint4*)&O[(w << 11) + ((lane * 8 + (w << 3)) & 2047)] = pk;
    }
    __syncthreads();

    float tn0 = 0.f, tn1 = 0.f, tn2 = 0.f, tn3 = 0.f;   // on-the-fly tail accs
    float bnext = 0.f;

    if (!isC) {
        // ---- prologue: stage Panel(0) + main(0) over full [0,512) -> Zp[0]
        if (w < 12) {
            const int pt = t - 256;
            const int sn = pt >> 2, sc = (pt & 3) << 4;
            const float* src = W + (size_t)sn * NCOLS + NIN + sc;
            float4 v0 = ((const float4*)src)[0];
            float4 v1 = ((const float4*)src)[1];
            float4 v2 = ((const float4*)src)[2];
            float4 v3 = ((const float4*)src)[3];
            v0.x *= C5; v0.y *= C5; v0.z *= C5; v0.w *= C5;
            v1.x *= C5; v1.y *= C5; v1.z *= C5; v1.w *= C5;
            v2.x *= C5; v2.y *= C5; v2.z *= C5; v2.w *= C5;
            v3.x *= C5; v3.y *= C5; v3.z *= C5; v3.w *= C5;
            float4* dst = (float4*)&Wt[0][sn * WTS + sc];
            dst[0] = v0; dst[1] = v1; dst[2] = v2; dst[3] = v3;
        }
        const int pw  = w - 4;          // 0..11
        const int ng  = pw / 3;         // node group 0..3
        const int ksp = pw - ng * 3;    // K-slot 0..2 (32-col chunks mod 3)
        floatx4 acc = {0.f, 0.f, 0.f, 0.f};
        const ushort* wbp = Wb + (size_t)((ng << 4) + m16) * NCOLS;
        for (int kk = ksp * 32; kk < NIN; kk += 96) {
            short8 a = *(const short8*)&O[arow + ((kk + (quad << 3) + arot) & 2047)];
            short8 b = *(const short8*)&wbp[kk + (quad << 3)];
            acc = __builtin_amdgcn_mfma_f32_16x16x32_bf16(a, b, acc, 0, 0, 0);
        }
        *(floatx4*)&Zp[0][(pw << 8) + (lane << 2)] = acc;
    } else {
        bnext = bias[ii];               // bias for block 0 (shared by all 4 rows)
    }
    __syncthreads();                    // barrier(0): Zp[0], Wt[0] visible

    for (int k = 0; k < NBLK; ++k) {
        if (isC) {
            // ================= consumer: chain block k, rows 4w..4w+3 ======
            const int i0 = k << 6;
            float bcur = bnext;
            if (k + 1 < NBLK) bnext = bias[((k + 1) << 6) + ii];

            const float* zp = &Zp[k & 1][0];
            const int zb = (ii >> 4) * 768;             // node-group * 3 waves * 256
            const int bb = (w << 6) + ((ii & 15) << 2); // rows 4w..4w+3 -> +q
            float z0 = zp[zb + bb + 0] + zp[zb + 256 + bb + 0] + zp[zb + 512 + bb + 0];
            float z1 = zp[zb + bb + 1] + zp[zb + 256 + bb + 1] + zp[zb + 512 + bb + 1];
            float z2 = zp[zb + bb + 2] + zp[zb + 256 + bb + 2] + zp[zb + 512 + bb + 2];
            float z3 = zp[zb + bb + 3] + zp[zb + 256 + bb + 3] + zp[zb + 512 + bb + 3];
            const float sb = C5 * bcur;
            float y0 = fmaf(C5, z0, tn0 + sb); tn0 = 0.f;
            float y1 = fmaf(C5, z1, tn1 + sb); tn1 = 0.f;
            float y2 = fmaf(C5, z2, tn2 + sb); tn2 = 0.f;
            float y3 = fmaf(C5, z3, tn3 + sb); tn3 = 0.f;

            const float* wrD = &Wt[k & 1][ii * WTS];
            const float* wrS = &Wt[k & 1][(64 + ii) * WTS];
            float4 d0 = *(const float4*)(wrD);
            float4 s0 = *(const float4*)(wrS);
            float4 d1 = *(const float4*)(wrD + 4);
            float4 s1 = *(const float4*)(wrS + 4);

            #define STEP(wdv, wsv, J) do { \
                float a0_ = rdlane(y0, (J)), a1_ = rdlane(y1, (J)); \
                float a2_ = rdlane(y2, (J)), a3_ = rdlane(y3, (J)); \
                float o0_ = sig2(a0_), o1_ = sig2(a1_); \
                float o2_ = sig2(a2_), o3_ = sig2(a3_); \
                y0 = fmaf((wdv), o0_, y0); tn0 = fmaf((wsv), o0_, tn0); \
                y1 = fmaf((wdv), o1_, y1); tn1 = fmaf((wsv), o1_, tn1); \
                y2 = fmaf((wdv), o2_, y2); tn2 = fmaf((wsv), o2_, tn2); \
                y3 = fmaf((wdv), o3_, y3); tn3 = fmaf((wsv), o3_, tn3); \
            } while (0)

            #pragma unroll
            for (int j0 = 0; j0 < 64; j0 += 8) {
                float4 pd0 = d0, ps0 = s0, pd1 = d1, ps1 = s1;
                if (j0 < 56) {                      // prefetch 2 groups ahead
                    pd0 = *(const float4*)(wrD + j0 + 8);
                    ps0 = *(const float4*)(wrS + j0 + 8);
                    pd1 = *(const float4*)(wrD + j0 + 12);
                    ps1 = *(const float4*)(wrS + j0 + 12);
                }
                STEP(d0.x, s0.x, j0 + 0); STEP(d0.y, s0.y, j0 + 1);
                STEP(d0.z, s0.z, j0 + 2); STEP(d0.w, s0.w, j0 + 3);
                STEP(d1.x, s1.x, j0 + 4); STEP(d1.y, s1.y, j0 + 5);
                STEP(d1.z, s1.z, j0 + 6); STEP(d1.w, s1.w, j0 + 7);
                d0 = pd0; s0 = ps0; d1 = pd1; s1 = ps1;
            }
            #undef STEP

            // lane ii's y is final after step ii (upper-tri zeros in memory)
            float f0 = sig2(y0), f1 = sig2(y1), f2 = sig2(y2), f3 = sig2(y3);
            const int r0 = (w << 2);
            O[((r0 + 0) << 11) + ((NIN + i0 + ii + ((r0 + 0) << 3)) & 2047)] = f2bf(f0);
            O[((r0 + 1) << 11) + ((NIN + i0 + ii + ((r0 + 1) << 3)) & 2047)] = f2bf(f1);
            O[((r0 + 2) << 11) + ((NIN + i0 + ii + ((r0 + 2) << 3)) & 2047)] = f2bf(f2);
            O[((r0 + 3) << 11) + ((NIN + i0 + ii + ((r0 + 3) << 3)) & 2047)] = f2bf(f3);
            const int g = i0 + ii;
            if (g >= OUT_BASE) {
                const long rg = (long)blockIdx.x * 16 + r0;
                float* op = out + rg * NOUT + (g - OUT_BASE);
                op[0]        = f0;
                op[NOUT]     = f1;
                op[2 * NOUT] = f2;
                op[3 * NOUT] = f3;
            }
        } else if (k + 1 < NBLK) {
            // ================= producer: block b = k+1 =====================
            const int b = k + 1;
            // stage Panel(b): rows e in [64b, 64b+128) clipped, cols [512+64b, +64)
            if (w < 12) {
                const int pt = t - 256;
                const int sn = pt >> 2, sc = (pt & 3) << 4;
                const int e = (b << 6) + sn;
                if (e < NEVAL) {
                    const float* src = W + (size_t)e * NCOLS + (NIN + (b << 6)) + sc;
                    float4 v0 = ((const float4*)src)[0];
                    float4 v1 = ((const float4*)src)[1];
                    float4 v2 = ((const float4*)src)[2];
                    float4 v3 = ((const float4*)src)[3];
                    v0.x *= C5; v0.y *= C5; v0.z *= C5; v0.w *= C5;
                    v1.x *= C5; v1.y *= C5; v1.z *= C5; v1.w *= C5;
                    v2.x *= C5; v2.y *= C5; v2.z *= C5; v2.w *= C5;
                    v3.x *= C5; v3.y *= C5; v3.z *= C5; v3.w *= C5;
                    float4* dst = (float4*)&Wt[b & 1][sn * WTS + sc];
                    dst[0] = v0; dst[1] = v1; dst[2] = v2; dst[3] = v3;
                }
            }
            // main(b): cols [0, 448+64b), 3-way K-split (chunk c: owner c%3)
            const int pw  = w - 4;
            const int ng  = pw / 3;
            const int ksp = pw - ng * 3;
            floatx4 acc = {0.f, 0.f, 0.f, 0.f};
            const ushort* wbp = Wb + (size_t)((b << 6) + (ng << 4) + m16) * NCOLS;
            const int hi = (NIN - BK) + (b << 6);
            #pragma unroll 4
            for (int kk = ksp * 32; kk < hi; kk += 96) {
                short8 a  = *(const short8*)&O[arow + ((kk + (quad << 3) + arot) & 2047)];
                short8 bb = *(const short8*)&wbp[kk + (quad << 3)];
                acc = __builtin_amdgcn_mfma_f32_16x16x32_bf16(a, bb, acc, 0, 0, 0);
            }
            *(floatx4*)&Zp[b & 1][(pw << 8) + (lane << 2)] = acc;
        }
        __syncthreads();            // end of slot k: Zp/Wt(k+1) + O(N_k) visible
    }
}

// ---------- launch ----------

extern "C" void kernel_launch(void* const* d_in, const int* in_sizes, int n_in,
                              void* d_out, int out_size, void* d_ws, size_t ws_size,
                              hipStream_t stream) {
    const float* x  = (const float*)d_in[0];   // [4096, 512]
    const float* W  = (const float*)d_in[1];   // [1536, 2048]
    const float* b  = (const float*)d_in[2];   // [1536]
    float* out = (float*)d_out;                // [4096, 256]
    ushort* Wb = (ushort*)d_ws;                // bf16 W copy (6.3 MB)

    int n8 = NEVAL * NCOLS / 8;
    wconv<<<n8 / 256, 256, 0, stream>>>(W, Wb, n8);
    ffnet<<<4096 / 16, 1024, 0, stream>>>(x, W, Wb, b, out);
}